// Round 7
// baseline (4040.309 us; speedup 1.0000x reference)
//
#include <hip/hip_runtime.h>
#include <math.h>

#define T_SEQ 512
#define B_SZ  64
#define I_DIM 512
#define H_DIM 1024

typedef __attribute__((ext_vector_type(8))) short     short8;
typedef __attribute__((ext_vector_type(4))) float     f32x4;

// ---------------- recurrence LDS geometry (carved from dynamic smem) ----------------
#define HROW   1032                      // staged h row stride in bf16 shorts (1024+8)
#define HPLANE (8 * HROW)                // single h plane, 8 batches -> 16512 B
#define RED_OFF HPLANE                   // red[] after the plane (short index)
#define RECUR_LDS_BYTES 148096           // forces 1 block/CU; ~25 KB used
#define RING 4                           // h ring slots (K>=2 proven safe)

__device__ __forceinline__ unsigned short f2bf_rn(float f) {
    unsigned u = __float_as_uint(f);
    unsigned r = u + 0x7fffu + ((u >> 16) & 1u);
    return (unsigned short)(r >> 16);
}
__device__ __forceinline__ float bf2f(unsigned short s) {
    return __uint_as_float(((unsigned)s) << 16);
}

// =====================================================================
// Kernel 0: split W_hh fp32 -> bf16 hi/lo planes (one-time prep)
// =====================================================================
__global__ __launch_bounds__(256) void wsplit_kernel(
    const float* __restrict__ W, unsigned short* __restrict__ Whi,
    unsigned short* __restrict__ Wlo)
{
    int i = blockIdx.x * 256 + threadIdx.x;          // grid covers 1024*1024
    float w = W[i];
    unsigned short hi = f2bf_rn(w);
    Whi[i] = hi;
    Wlo[i] = f2bf_rn(w - bf2f(hi));
}

// =====================================================================
// Kernel 1: xW[tloc][b][h] = input[b][t0+tloc][:] . W_ih[h][:] + b_ih[h]
// (proven rounds 2-6)
// =====================================================================
__global__ __launch_bounds__(256) void xw_gemm_kernel(
    const float* __restrict__ input, const float* __restrict__ W_ih,
    const float* __restrict__ b_ih, float* __restrict__ xw,
    int t0)
{
    __shared__ float Ash[32 * 68];
    __shared__ float Bsh[32 * 68];

    const int bm  = blockIdx.x >> 4;
    const int bn  = blockIdx.x & 15;
    const int tid = threadIdx.x;
    const int tx  = tid & 15;
    const int ty  = tid >> 4;

    const int t = t0 + bm;
    const float* Abase = input + (size_t)t * I_DIM;
    const float* Bbase = W_ih + (size_t)(bn * 64) * I_DIM;

    float acc[4][4] = {};

    for (int kt = 0; kt < I_DIM; kt += 32) {
        #pragma unroll
        for (int p = 0; p < 2; ++p) {
            int idx = tid + p * 256;
            int row = idx >> 3;
            int c4  = (idx & 7) << 2;
            float4 a = *(const float4*)(Abase + (size_t)row * (T_SEQ * I_DIM) + kt + c4);
            float4 b = *(const float4*)(Bbase + (size_t)row * I_DIM + kt + c4);
            Ash[(c4 + 0) * 68 + row] = a.x; Ash[(c4 + 1) * 68 + row] = a.y;
            Ash[(c4 + 2) * 68 + row] = a.z; Ash[(c4 + 3) * 68 + row] = a.w;
            Bsh[(c4 + 0) * 68 + row] = b.x; Bsh[(c4 + 1) * 68 + row] = b.y;
            Bsh[(c4 + 2) * 68 + row] = b.z; Bsh[(c4 + 3) * 68 + row] = b.w;
        }
        __syncthreads();
        #pragma unroll
        for (int k = 0; k < 32; ++k) {
            float4 a4 = *(const float4*)&Ash[k * 68 + ty * 4];
            float4 b4 = *(const float4*)&Bsh[k * 68 + tx * 4];
            float av[4] = {a4.x, a4.y, a4.z, a4.w};
            float bv[4] = {b4.x, b4.y, b4.z, b4.w};
            #pragma unroll
            for (int i = 0; i < 4; ++i)
                #pragma unroll
                for (int j = 0; j < 4; ++j)
                    acc[i][j] += av[i] * bv[j];
        }
        __syncthreads();
    }

    const int ncol = bn * 64 + tx * 4;
    float4 bias = *(const float4*)(b_ih + ncol);
    #pragma unroll
    for (int i = 0; i < 4; ++i) {
        int b = ty * 4 + i;
        float4 v;
        v.x = acc[i][0] + bias.x; v.y = acc[i][1] + bias.y;
        v.z = acc[i][2] + bias.z; v.w = acc[i][3] + bias.w;
        *(float4*)(xw + ((size_t)bm * B_SZ + b) * H_DIM + ncol) = v;
    }
}

// =====================================================================
// Kernel 2: persistent MFMA recurrence, TAG-IN-DATA, DUAL-PUBLISH.
//  Producers publish tagged h_t ((t<<16)|bf16) to BOTH:
//    fastbuf: plain store  -> lands in the producer XCD's L2
//    slowbuf: sc1 store    -> MALL (round-5-proven lane)
//  Consumers decide ONCE per launch which lane to poll:
//    all 32 group members on my XCD (via HW_REG_XCC_ID, published+tagged)
//      -> poll fastbuf with sc0 loads (same-L2 exchange, ~0.1-0.2us RTT)
//    else -> poll slowbuf sc1 (proven).
//  The decision is consumer-side only (both lanes always written), so a
//  wrong/mixed decision cannot lose data; a wrong-fast choice trips a
//  sticky 64-fail escalation to the slow lane. Deadlock impossible.
//  Stale xcdtag across graph replays: bounded by the same escalation.
// =====================================================================
__global__ __launch_bounds__(256, 1) void elman_recur_kernel(
    const float* __restrict__ xw,            // [tc][64][1024]
    const unsigned short* __restrict__ Whi,  // [1024][1024] bf16 hi plane
    const unsigned short* __restrict__ Wlo,  // [1024][1024] bf16 lo plane
    unsigned int* __restrict__ fastbuf,      // [RING][64][1024] tagged words (L2 lane)
    unsigned int* __restrict__ slowbuf,      // [RING][64][1024] tagged words (MALL lane)
    unsigned int* __restrict__ xcdtag,       // [256] 0x58000000|xcd per block
    float* __restrict__ out,                 // [64][512][1024]
    int t0, int tc)
{
    extern __shared__ __align__(16) short smem[];
    short* hA  = smem;                        // [8][HROW] bf16 (single plane)
    float* red = (float*)(smem + RED_OFF);    // [4][2][16][16]

    const int tid = threadIdx.x;
    const int bg  = blockIdx.x & 7;     // batch group
    const int js  = blockIdx.x >> 3;    // j slice
    const int w   = tid >> 6;           // wave id (K-split)
    const int l   = tid & 63;           // lane
    const int b   = tid & 7;            // epilogue: batch
    const int jl  = tid >> 3;           // epilogue: local j (0..31)
    const int jg  = js * 32 + jl;
    const int bgl = bg * 8 + b;

    // ---- one-time: W B-fragments into registers (k-contiguous, B^T layout) ----
    short8 Bhi[2][8], Blo[2][8];
    {
        const int n  = l & 15;
        const int kb = (l >> 4) * 8;
        #pragma unroll
        for (int t2 = 0; t2 < 2; ++t2) {
            const unsigned short* rhi = Whi + (size_t)(js * 32 + t2 * 16 + n) * H_DIM;
            const unsigned short* rlo = Wlo + (size_t)(js * 32 + t2 * 16 + n) * H_DIM;
            #pragma unroll
            for (int ks = 0; ks < 8; ++ks) {
                int k = w * 256 + ks * 32 + kb;
                Bhi[t2][ks] = *(const short8*)(rhi + k);
                Blo[t2][ks] = *(const short8*)(rlo + k);
            }
        }
    }

    // ---- one-time: XCD-locality check for the fast lane ----
    unsigned myxcd;
    asm volatile("s_getreg_b32 %0, hwreg(HW_REG_XCC_ID)" : "=s"(myxcd));
    if (tid == 0)
        __hip_atomic_store(xcdtag + blockIdx.x, 0x58000000u | (myxcd & 0xffu),
                           __ATOMIC_RELAXED, __HIP_MEMORY_SCOPE_AGENT);
    bool fastok;
    {
        unsigned e;
        int pub;
        do {   // wait until my whole group has published (magic byte 0x58)
            e = __hip_atomic_load(xcdtag + bg + (tid & 31) * 8, __ATOMIC_RELAXED,
                                  __HIP_MEMORY_SCOPE_AGENT);
            pub = __syncthreads_and((e >> 24) == 0x58u);
        } while (!pub);
        fastok = (bool)__syncthreads_and((e & 0xffu) == (myxcd & 0xffu));
    }

    for (int s = 0; s < tc; ++s) {
        const int t = t0 + s;

        // prefetch xw (independent of h) before any waiting
        float pre = xw[((size_t)s * B_SZ + bgl) * H_DIM + jg];

        if (t > 0) {
            const unsigned tagw = (unsigned)(t - 1);
            const size_t grpoff = (size_t)((t - 1) & (RING - 1)) * B_SZ * H_DIM
                                + (size_t)bg * 8 * H_DIM;
            const unsigned long long* gf = (const unsigned long long*)(fastbuf + grpoff);
            const unsigned long long* gs = (const unsigned long long*)(slowbuf + grpoff);

            // ---- poll: reload group h (8x1024 tagged words) until all fresh ----
            unsigned long long v[16];
            int fails = 0;
            for (;;) {
                if (fastok) {
                    // sc0: bypass L1, served by this XCD's L2 (producer wrote it plain)
                    #pragma unroll
                    for (int p = 0; p < 16; ++p) {
                        const unsigned long long* ap = gf + p * 256 + tid;
                        asm volatile("global_load_dwordx2 %0, %1, off sc0"
                                     : "=v"(v[p]) : "v"(ap));
                    }
                    asm volatile("s_waitcnt vmcnt(0)" ::: "memory");
                } else {
                    // MALL lane (round-5-proven)
                    #pragma unroll
                    for (int p = 0; p < 16; ++p)
                        v[p] = __hip_atomic_load(gs + p * 256 + tid, __ATOMIC_RELAXED,
                                                 __HIP_MEMORY_SCOPE_AGENT);
                }
                int ok = 1;
                #pragma unroll
                for (int p = 0; p < 16; ++p) {
                    ok &= (((unsigned)(v[p] >> 16) & 0xffffu) == tagw);
                    ok &= ((unsigned)(v[p] >> 48) == tagw);
                }
                if (__syncthreads_and(ok)) break;
                if (fastok && ++fails >= 64) fastok = false;  // sticky, block-uniform
            }

            // ---- unpack payloads -> bf16 plane in LDS ----
            #pragma unroll
            for (int p = 0; p < 16; ++p) {
                int q   = p * 256 + tid;          // u64 pair index 0..4095
                int row = q >> 9;                 // 0..7
                int c   = (q & 511) * 2;          // 0..1022
                unsigned lo32 = (unsigned)v[p];
                unsigned hi32 = (unsigned)(v[p] >> 32);
                *(unsigned*)(hA + row * HROW + c) = (lo32 & 0xffffu) | (hi32 << 16);
            }
            __syncthreads();   // B1: staging done

            // ---- MFMA: this wave's K range, 2 N-tiles, 2 passes (Whi+Wlo) ----
            f32x4 acc0 = {0.f, 0.f, 0.f, 0.f};
            f32x4 acc1 = {0.f, 0.f, 0.f, 0.f};
            const short* aAb = hA + (l & 7) * HROW + w * 256 + ((l >> 4) * 8);
            #pragma unroll
            for (int ks = 0; ks < 8; ++ks) {
                short8 ah = *(const short8*)(aAb + ks * 32);
                acc0 = __builtin_amdgcn_mfma_f32_16x16x32_bf16(ah, Bhi[0][ks], acc0, 0, 0, 0);
                acc1 = __builtin_amdgcn_mfma_f32_16x16x32_bf16(ah, Bhi[1][ks], acc1, 0, 0, 0);
                acc0 = __builtin_amdgcn_mfma_f32_16x16x32_bf16(ah, Blo[0][ks], acc0, 0, 0, 0);
                acc1 = __builtin_amdgcn_mfma_f32_16x16x32_bf16(ah, Blo[1][ks], acc1, 0, 0, 0);
            }
            // partials -> LDS  (D layout: col = l&15, row = (l>>4)*4 + reg)
            *(f32x4*)&red[((w * 2 + 0) * 16 + (l & 15)) * 16 + (l >> 4) * 4] = acc0;
            *(f32x4*)&red[((w * 2 + 1) * 16 + (l & 15)) * 16 + (l >> 4) * 4] = acc1;
            __syncthreads();   // B2: partials visible (also fences hA reads)

            // reduce 4 wave-partials for this thread's (b, jl)
            const int tt = jl >> 4, c = jl & 15;
            #pragma unroll
            for (int w2 = 0; w2 < 4; ++w2)
                pre += red[((w2 * 2 + tt) * 16 + c) * 16 + b];
        }

        float hval = tanhf(pre);

        // publish tagged h_t to BOTH lanes (fire-and-forget; store IS the signal)
        unsigned packed = ((unsigned)t << 16) | (unsigned)f2bf_rn(hval);
        const size_t hoff = (size_t)(t & (RING - 1)) * B_SZ * H_DIM
                          + (size_t)bgl * H_DIM + jg;
        *(volatile unsigned*)(fastbuf + hoff) = packed;               // local-L2 lane
        __hip_atomic_store(slowbuf + hoff, packed,
                           __ATOMIC_RELAXED, __HIP_MEMORY_SCOPE_AGENT); // MALL lane
        __builtin_nontemporal_store(hval, out + ((size_t)bgl * T_SEQ + t) * H_DIM + jg);
    }
}

// =====================================================================
extern "C" void kernel_launch(void* const* d_in, const int* in_sizes, int n_in,
                              void* d_out, int out_size, void* d_ws, size_t ws_size,
                              hipStream_t stream) {
    (void)in_sizes; (void)n_in; (void)out_size;
    const float* input = (const float*)d_in[0];   // [64,512,512]
    const float* W_ih  = (const float*)d_in[1];   // [1024,512]
    const float* b_ih  = (const float*)d_in[2];   // [1024]
    const float* W_hh  = (const float*)d_in[3];   // [1024,1024]
    float* out = (float*)d_out;

    char* ws = (char*)d_ws;
    // layout: fast ring (1M) | slow ring (1M) | Whi (2M) | Wlo (2M) | xcdtag (4K) | xw
    unsigned int*   fastbuf = (unsigned int*)ws;
    unsigned int*   slowbuf = (unsigned int*)(ws + (1 << 20));
    unsigned short* Whi     = (unsigned short*)(ws + (2 << 20));
    unsigned short* Wlo     = (unsigned short*)(ws + (4 << 20));
    unsigned int*   xcdtag  = (unsigned int*)(ws + (6 << 20));
    const size_t    xw_off  = (size_t)(6 << 20) + (64 << 10);
    float*          xwbuf   = (float*)(ws + xw_off);

    const size_t slice_bytes = (size_t)B_SZ * H_DIM * sizeof(float);  // 256 KB/t
    size_t avail = ws_size > xw_off ? ws_size - xw_off : 0;
    int Tc = (int)(avail / slice_bytes);
    if (Tc > T_SEQ) Tc = T_SEQ;
    if (Tc < 1)     Tc = 1;

    hipFuncSetAttribute((const void*)elman_recur_kernel,
                        hipFuncAttributeMaxDynamicSharedMemorySize,
                        RECUR_LDS_BYTES);

    // clear xcdtag each call (deterministic; removes cross-replay staleness)
    hipMemsetAsync(xcdtag, 0, 256 * sizeof(unsigned int), stream);

    // one-time W split (stream-ordered; coherent for later kernels)
    wsplit_kernel<<<dim3(4096), dim3(256), 0, stream>>>(W_hh, Whi, Wlo);

    for (int t0 = 0; t0 < T_SEQ; t0 += Tc) {
        int tc = (T_SEQ - t0 < Tc) ? (T_SEQ - t0) : Tc;

        xw_gemm_kernel<<<dim3((unsigned)tc * 16), dim3(256), 0, stream>>>(
            input, W_ih, b_ih, xwbuf, t0);

        // plain launch (graph-capture-safe): 148 KB LDS -> 1 block/CU,
        // grid 256 == CU count -> co-resident.
        elman_recur_kernel<<<dim3(256), dim3(256), RECUR_LDS_BYTES, stream>>>(
            xwbuf, Whi, Wlo, fastbuf, slowbuf, xcdtag, out, t0, tc);
    }
}

// Round 8
// 2463.557 us; speedup vs baseline: 1.6400x; 1.6400x over previous
//
#include <hip/hip_runtime.h>
#include <math.h>

#define T_SEQ 512
#define B_SZ  64
#define I_DIM 512
#define H_DIM 1024

typedef __attribute__((ext_vector_type(8))) short     short8;
typedef __attribute__((ext_vector_type(4))) float     f32x4;

// ---------------- recurrence LDS geometry (carved from dynamic smem) ----------------
#define HROW   1032                      // staged h row stride in bf16 shorts (1024+8)
#define HPLANE (8 * HROW)                // single h plane, 8 batches -> 16512 B
#define RED_OFF HPLANE                   // red[] after the plane (short index)
#define RECUR_LDS_BYTES 148096           // forces 1 block/CU; ~25 KB used
#define RING 4                           // h ring slots (K>=2 proven safe)

__device__ __forceinline__ unsigned short f2bf_rn(float f) {
    unsigned u = __float_as_uint(f);
    unsigned r = u + 0x7fffu + ((u >> 16) & 1u);
    return (unsigned short)(r >> 16);
}
__device__ __forceinline__ float bf2f(unsigned short s) {
    return __uint_as_float(((unsigned)s) << 16);
}

// =====================================================================
// Kernel 0: split W_hh fp32 -> bf16 hi/lo planes (one-time prep)
// =====================================================================
__global__ __launch_bounds__(256) void wsplit_kernel(
    const float* __restrict__ W, unsigned short* __restrict__ Whi,
    unsigned short* __restrict__ Wlo)
{
    int i = blockIdx.x * 256 + threadIdx.x;          // grid covers 1024*1024
    float w = W[i];
    unsigned short hi = f2bf_rn(w);
    Whi[i] = hi;
    Wlo[i] = f2bf_rn(w - bf2f(hi));
}

// =====================================================================
// Kernel 1: xW[tloc][b][h] = input[b][t0+tloc][:] . W_ih[h][:] + b_ih[h]
// (proven rounds 2-7)
// =====================================================================
__global__ __launch_bounds__(256) void xw_gemm_kernel(
    const float* __restrict__ input, const float* __restrict__ W_ih,
    const float* __restrict__ b_ih, float* __restrict__ xw,
    int t0)
{
    __shared__ float Ash[32 * 68];
    __shared__ float Bsh[32 * 68];

    const int bm  = blockIdx.x >> 4;
    const int bn  = blockIdx.x & 15;
    const int tid = threadIdx.x;
    const int tx  = tid & 15;
    const int ty  = tid >> 4;

    const int t = t0 + bm;
    const float* Abase = input + (size_t)t * I_DIM;
    const float* Bbase = W_ih + (size_t)(bn * 64) * I_DIM;

    float acc[4][4] = {};

    for (int kt = 0; kt < I_DIM; kt += 32) {
        #pragma unroll
        for (int p = 0; p < 2; ++p) {
            int idx = tid + p * 256;
            int row = idx >> 3;
            int c4  = (idx & 7) << 2;
            float4 a = *(const float4*)(Abase + (size_t)row * (T_SEQ * I_DIM) + kt + c4);
            float4 b = *(const float4*)(Bbase + (size_t)row * I_DIM + kt + c4);
            Ash[(c4 + 0) * 68 + row] = a.x; Ash[(c4 + 1) * 68 + row] = a.y;
            Ash[(c4 + 2) * 68 + row] = a.z; Ash[(c4 + 3) * 68 + row] = a.w;
            Bsh[(c4 + 0) * 68 + row] = b.x; Bsh[(c4 + 1) * 68 + row] = b.y;
            Bsh[(c4 + 2) * 68 + row] = b.z; Bsh[(c4 + 3) * 68 + row] = b.w;
        }
        __syncthreads();
        #pragma unroll
        for (int k = 0; k < 32; ++k) {
            float4 a4 = *(const float4*)&Ash[k * 68 + ty * 4];
            float4 b4 = *(const float4*)&Bsh[k * 68 + tx * 4];
            float av[4] = {a4.x, a4.y, a4.z, a4.w};
            float bv[4] = {b4.x, b4.y, b4.z, b4.w};
            #pragma unroll
            for (int i = 0; i < 4; ++i)
                #pragma unroll
                for (int j = 0; j < 4; ++j)
                    acc[i][j] += av[i] * bv[j];
        }
        __syncthreads();
    }

    const int ncol = bn * 64 + tx * 4;
    float4 bias = *(const float4*)(b_ih + ncol);
    #pragma unroll
    for (int i = 0; i < 4; ++i) {
        int b = ty * 4 + i;
        float4 v;
        v.x = acc[i][0] + bias.x; v.y = acc[i][1] + bias.y;
        v.z = acc[i][2] + bias.z; v.w = acc[i][3] + bias.w;
        *(float4*)(xw + ((size_t)bm * B_SZ + b) * H_DIM + ncol) = v;
    }
}

// =====================================================================
// Kernel 2: persistent MFMA recurrence, TAG-IN-DATA, TWO-PHASE POLL.
//  R5 core (single sc1 publish, 4-slot tagged ring, no fences/flags/RMW),
//  plus: poll phase A reads ONLY row 0 of the group tile (4 KB/block/iter,
//  8x less MALL traffic). Row 0 holds 32 words from EVERY producer block
//  (its threads b=0, jl=0..31), so it is a complete per-producer sentinel.
//  Phase B then loads the full 32 KB once and verifies every tag; loops if
//  stragglers remain (rare — a block's 256 stores issue within ~100ns).
//  Correctness identical to R5: consumption still gated on all-tags-fresh;
//  stale-tag matches can only deliver bit-identical prior-replay values.
// =====================================================================
__global__ __launch_bounds__(256, 1) void elman_recur_kernel(
    const float* __restrict__ xw,            // [tc][64][1024]
    const unsigned short* __restrict__ Whi,  // [1024][1024] bf16 hi plane
    const unsigned short* __restrict__ Wlo,  // [1024][1024] bf16 lo plane
    unsigned int* __restrict__ hbuf,         // [RING][64][1024] tagged words
    float* __restrict__ out,                 // [64][512][1024]
    int t0, int tc)
{
    extern __shared__ __align__(16) short smem[];
    short* hA  = smem;                        // [8][HROW] bf16 (single plane)
    float* red = (float*)(smem + RED_OFF);    // [4][2][16][16]

    const int tid = threadIdx.x;
    const int bg  = blockIdx.x & 7;     // batch group
    const int js  = blockIdx.x >> 3;    // j slice
    const int w   = tid >> 6;           // wave id (K-split)
    const int l   = tid & 63;           // lane
    const int b   = tid & 7;            // epilogue: batch
    const int jl  = tid >> 3;           // epilogue: local j (0..31)
    const int jg  = js * 32 + jl;
    const int bgl = bg * 8 + b;

    // ---- one-time: W B-fragments into registers (k-contiguous, B^T layout) ----
    short8 Bhi[2][8], Blo[2][8];
    {
        const int n  = l & 15;
        const int kb = (l >> 4) * 8;
        #pragma unroll
        for (int t2 = 0; t2 < 2; ++t2) {
            const unsigned short* rhi = Whi + (size_t)(js * 32 + t2 * 16 + n) * H_DIM;
            const unsigned short* rlo = Wlo + (size_t)(js * 32 + t2 * 16 + n) * H_DIM;
            #pragma unroll
            for (int ks = 0; ks < 8; ++ks) {
                int k = w * 256 + ks * 32 + kb;
                Bhi[t2][ks] = *(const short8*)(rhi + k);
                Blo[t2][ks] = *(const short8*)(rlo + k);
            }
        }
    }

    for (int s = 0; s < tc; ++s) {
        const int t = t0 + s;

        // prefetch xw (independent of h) before any waiting
        float pre = xw[((size_t)s * B_SZ + bgl) * H_DIM + jg];

        if (t > 0) {
            const unsigned tagw = (unsigned)(t - 1);
            const unsigned long long* grp = (const unsigned long long*)
                (hbuf + (size_t)((t - 1) & (RING - 1)) * B_SZ * H_DIM
                      + (size_t)bg * 8 * H_DIM);

            // ---- Phase A: sentinel poll on row 0 only (4 KB/block/iter) ----
            for (;;) {
                unsigned long long s0 =
                    __hip_atomic_load(grp + tid, __ATOMIC_RELAXED,
                                      __HIP_MEMORY_SCOPE_AGENT);
                unsigned long long s1 =
                    __hip_atomic_load(grp + 256 + tid, __ATOMIC_RELAXED,
                                      __HIP_MEMORY_SCOPE_AGENT);
                int ok = (((unsigned)(s0 >> 16) & 0xffffu) == tagw);
                ok &= ((unsigned)(s0 >> 48) == tagw);
                ok &= (((unsigned)(s1 >> 16) & 0xffffu) == tagw);
                ok &= ((unsigned)(s1 >> 48) == tagw);
                if (__syncthreads_and(ok)) break;
            }

            // ---- Phase B: full load + verify (typically one iteration) ----
            unsigned long long v[16];
            for (;;) {
                #pragma unroll
                for (int p = 0; p < 16; ++p)
                    v[p] = __hip_atomic_load(grp + p * 256 + tid, __ATOMIC_RELAXED,
                                             __HIP_MEMORY_SCOPE_AGENT);
                int ok = 1;
                #pragma unroll
                for (int p = 0; p < 16; ++p) {
                    ok &= (((unsigned)(v[p] >> 16) & 0xffffu) == tagw);
                    ok &= ((unsigned)(v[p] >> 48) == tagw);
                }
                if (__syncthreads_and(ok)) break;
            }

            // ---- unpack payloads -> bf16 plane in LDS ----
            #pragma unroll
            for (int p = 0; p < 16; ++p) {
                int q   = p * 256 + tid;          // u64 pair index 0..4095
                int row = q >> 9;                 // 0..7
                int c   = (q & 511) * 2;          // 0..1022
                unsigned lo32 = (unsigned)v[p];
                unsigned hi32 = (unsigned)(v[p] >> 32);
                *(unsigned*)(hA + row * HROW + c) = (lo32 & 0xffffu) | (hi32 << 16);
            }
            __syncthreads();   // B1: staging done

            // ---- MFMA: this wave's K range, 2 N-tiles, 2 passes (Whi+Wlo) ----
            f32x4 acc0 = {0.f, 0.f, 0.f, 0.f};
            f32x4 acc1 = {0.f, 0.f, 0.f, 0.f};
            const short* aAb = hA + (l & 7) * HROW + w * 256 + ((l >> 4) * 8);
            #pragma unroll
            for (int ks = 0; ks < 8; ++ks) {
                short8 ah = *(const short8*)(aAb + ks * 32);
                acc0 = __builtin_amdgcn_mfma_f32_16x16x32_bf16(ah, Bhi[0][ks], acc0, 0, 0, 0);
                acc1 = __builtin_amdgcn_mfma_f32_16x16x32_bf16(ah, Bhi[1][ks], acc1, 0, 0, 0);
                acc0 = __builtin_amdgcn_mfma_f32_16x16x32_bf16(ah, Blo[0][ks], acc0, 0, 0, 0);
                acc1 = __builtin_amdgcn_mfma_f32_16x16x32_bf16(ah, Blo[1][ks], acc1, 0, 0, 0);
            }
            // partials -> LDS  (D layout: col = l&15, row = (l>>4)*4 + reg)
            *(f32x4*)&red[((w * 2 + 0) * 16 + (l & 15)) * 16 + (l >> 4) * 4] = acc0;
            *(f32x4*)&red[((w * 2 + 1) * 16 + (l & 15)) * 16 + (l >> 4) * 4] = acc1;
            __syncthreads();   // B2: partials visible (also fences hA reads)

            // reduce 4 wave-partials for this thread's (b, jl)
            const int tt = jl >> 4, c = jl & 15;
            #pragma unroll
            for (int w2 = 0; w2 < 4; ++w2)
                pre += red[((w2 * 2 + tt) * 16 + c) * 16 + b];
        }

        float hval = tanhf(pre);

        // publish tagged h_t (the store IS the completion signal)
        unsigned packed = ((unsigned)t << 16) | (unsigned)f2bf_rn(hval);
        __hip_atomic_store(hbuf + (size_t)(t & (RING - 1)) * B_SZ * H_DIM
                                + (size_t)bgl * H_DIM + jg,
                           packed, __ATOMIC_RELAXED, __HIP_MEMORY_SCOPE_AGENT);
        __builtin_nontemporal_store(hval, out + ((size_t)bgl * T_SEQ + t) * H_DIM + jg);
        // no drain, no flag, no atomic RMW — next step's poll validates arrival
    }
}

// =====================================================================
extern "C" void kernel_launch(void* const* d_in, const int* in_sizes, int n_in,
                              void* d_out, int out_size, void* d_ws, size_t ws_size,
                              hipStream_t stream) {
    (void)in_sizes; (void)n_in; (void)out_size;
    const float* input = (const float*)d_in[0];   // [64,512,512]
    const float* W_ih  = (const float*)d_in[1];   // [1024,512]
    const float* b_ih  = (const float*)d_in[2];   // [1024]
    const float* W_hh  = (const float*)d_in[3];   // [1024,1024]
    float* out = (float*)d_out;

    char* ws = (char*)d_ws;
    // layout: hbuf ring (1M) | Whi (2M @1M) | Wlo (2M @3M) | xw (@5M)
    unsigned int*   hbuf  = (unsigned int*)ws;
    unsigned short* Whi   = (unsigned short*)(ws + (1 << 20));
    unsigned short* Wlo   = (unsigned short*)(ws + (3 << 20));
    float*          xwbuf = (float*)(ws + (5 << 20));

    const size_t slice_bytes = (size_t)B_SZ * H_DIM * sizeof(float);  // 256 KB/t
    size_t avail = ws_size > (size_t)(5 << 20) ? ws_size - (size_t)(5 << 20) : 0;
    int Tc = (int)(avail / slice_bytes);
    if (Tc > T_SEQ) Tc = T_SEQ;
    if (Tc < 1)     Tc = 1;

    hipFuncSetAttribute((const void*)elman_recur_kernel,
                        hipFuncAttributeMaxDynamicSharedMemorySize,
                        RECUR_LDS_BYTES);

    // one-time W split (stream-ordered; coherent for later kernels)
    wsplit_kernel<<<dim3(4096), dim3(256), 0, stream>>>(W_hh, Whi, Wlo);

    for (int t0 = 0; t0 < T_SEQ; t0 += Tc) {
        int tc = (T_SEQ - t0 < Tc) ? (T_SEQ - t0) : Tc;

        xw_gemm_kernel<<<dim3((unsigned)tc * 16), dim3(256), 0, stream>>>(
            input, W_ih, b_ih, xwbuf, t0);

        // plain launch (graph-capture-safe, proven): 148 KB LDS -> 1 block/CU,
        // grid 256 == CU count -> co-resident.
        elman_recur_kernel<<<dim3(256), dim3(256), RECUR_LDS_BYTES, stream>>>(
            xwbuf, Whi, Wlo, hbuf, out, t0, tc);
    }
}

// Round 9
// 1841.186 us; speedup vs baseline: 2.1944x; 1.3380x over previous
//
#include <hip/hip_runtime.h>
#include <math.h>

#define T_SEQ 512
#define B_SZ  64
#define I_DIM 512
#define H_DIM 1024

typedef __attribute__((ext_vector_type(8))) short     short8;
typedef __attribute__((ext_vector_type(4))) float     f32x4;

// ---------------- recurrence LDS geometry (carved from dynamic smem) ----------------
#define HROW   1032                      // staged h row stride in bf16 shorts (1024+8)
#define HPLANE (8 * HROW)                // single h plane, 8 batches -> 16512 B
#define RED_OFF HPLANE                   // red[] after the plane (short index)
#define RECUR_LDS_BYTES 148096           // forces 1 block/CU; ~25 KB used
#define RING 4                           // h ring slots (K>=2 proven safe)

// ---------------- xw MFMA GEMM geometry ----------------
#define XKP 40                           // padded k-row stride (shorts): 80B -> 16B aligned, 2-way banks (free)

__device__ __forceinline__ unsigned short f2bf_rn(float f) {
    unsigned u = __float_as_uint(f);
    unsigned r = u + 0x7fffu + ((u >> 16) & 1u);
    return (unsigned short)(r >> 16);
}
__device__ __forceinline__ float bf2f(unsigned short s) {
    return __uint_as_float(((unsigned)s) << 16);
}

// =====================================================================
// Kernel 0: split fp32 matrix -> bf16 hi/lo planes (one-time prep)
// =====================================================================
__global__ __launch_bounds__(256) void wsplit_kernel(
    const float* __restrict__ W, unsigned short* __restrict__ Whi,
    unsigned short* __restrict__ Wlo, int n)
{
    int i = blockIdx.x * 256 + threadIdx.x;
    if (i < n) {
        float w = W[i];
        unsigned short hi = f2bf_rn(w);
        Whi[i] = hi;
        Wlo[i] = f2bf_rn(w - bf2f(hi));
    }
}

// =====================================================================
// Kernel 1 (NEW): MFMA xw GEMM.  xw[s][b][h] = x[b][t0+s][:].W_ih[h][:] + b_ih
//  Tile M=128 (t-rows of one batch) x N=128 (h) x K=512, 3-pass hi/lo split:
//  xhi*Whi + xlo*Whi + xhi*Wlo  (fp32-grade; x split done on the fly in
//  staging).  Fragment maps copied verbatim from the verified recurrence
//  kernel (A/B row = lane&15, k = (lane>>4)*8; D row=(l>>4)*4+r, col=l&15).
//  Grid id = hch*(64*ntch) + tch*64 + b  -> the 8 hch-siblings sharing an
//  x-tile differ by multiples of 64 (==0 mod 8) -> same XCD -> L2 reuse.
// =====================================================================
__global__ __launch_bounds__(256) void xw_mfma_kernel(
    const float* __restrict__ input,         // [64][512][512] fp32
    const unsigned short* __restrict__ Whi,  // [1024][512] bf16 hi
    const unsigned short* __restrict__ Wlo,  // [1024][512] bf16 lo
    const float* __restrict__ b_ih,          // [1024]
    float* __restrict__ xw,                  // [tc][64][1024] fp32
    int t0, int ntch)
{
    __shared__ short xhi[128 * XKP];
    __shared__ short xlo[128 * XKP];
    __shared__ short whi[128 * XKP];
    __shared__ short wlo[128 * XKP];

    const int tid = threadIdx.x;
    const int per = 64 * ntch;
    const int grp = blockIdx.x % per;
    const int hch = blockIdx.x / per;
    const int b   = grp & 63;
    const int tch = grp >> 6;
    const int n0  = hch * 128;
    const int w   = tid >> 6;
    const int l   = tid & 63;

    const float* xsrc = input + ((size_t)b * T_SEQ + t0 + tch * 128) * I_DIM;
    const unsigned short* whsrc = Whi + (size_t)n0 * I_DIM;
    const unsigned short* wlsrc = Wlo + (size_t)n0 * I_DIM;

    f32x4 acc[8][2] = {};

    const int srow = tid >> 1;         // 0..127
    const int skq  = (tid & 1) * 16;   // 0 or 16

    for (int kt = 0; kt < I_DIM; kt += 32) {
        // ---- stage x: 16 fp32 -> hi/lo bf16 ----
        {
            const float* p = xsrc + (size_t)srow * I_DIM + kt + skq;
            union S8 { short s[8]; short8 v; };
            S8 h0, h1, l0, l1;
            #pragma unroll
            for (int i = 0; i < 8; ++i) {
                float f = p[i];
                unsigned short hh = f2bf_rn(f);
                h0.s[i] = (short)hh; l0.s[i] = (short)f2bf_rn(f - bf2f(hh));
            }
            #pragma unroll
            for (int i = 0; i < 8; ++i) {
                float f = p[8 + i];
                unsigned short hh = f2bf_rn(f);
                h1.s[i] = (short)hh; l1.s[i] = (short)f2bf_rn(f - bf2f(hh));
            }
            *(short8*)&xhi[srow * XKP + skq]     = h0.v;
            *(short8*)&xhi[srow * XKP + skq + 8] = h1.v;
            *(short8*)&xlo[srow * XKP + skq]     = l0.v;
            *(short8*)&xlo[srow * XKP + skq + 8] = l1.v;
        }
        // ---- stage W hi/lo (already bf16): straight 16B copies ----
        {
            const unsigned short* ph = whsrc + (size_t)srow * I_DIM + kt + skq;
            const unsigned short* pl = wlsrc + (size_t)srow * I_DIM + kt + skq;
            *(short8*)&whi[srow * XKP + skq]     = *(const short8*)(ph);
            *(short8*)&whi[srow * XKP + skq + 8] = *(const short8*)(ph + 8);
            *(short8*)&wlo[srow * XKP + skq]     = *(const short8*)(pl);
            *(short8*)&wlo[srow * XKP + skq + 8] = *(const short8*)(pl + 8);
        }
        __syncthreads();

        short8 bh[2], bl[2];
        #pragma unroll
        for (int ni = 0; ni < 2; ++ni) {
            int brow = w * 32 + ni * 16 + (l & 15);
            bh[ni] = *(const short8*)&whi[brow * XKP + (l >> 4) * 8];
            bl[ni] = *(const short8*)&wlo[brow * XKP + (l >> 4) * 8];
        }
        #pragma unroll
        for (int mi = 0; mi < 8; ++mi) {
            int arow = mi * 16 + (l & 15);
            short8 ah = *(const short8*)&xhi[arow * XKP + (l >> 4) * 8];
            short8 al = *(const short8*)&xlo[arow * XKP + (l >> 4) * 8];
            #pragma unroll
            for (int ni = 0; ni < 2; ++ni) {
                acc[mi][ni] = __builtin_amdgcn_mfma_f32_16x16x32_bf16(ah, bh[ni], acc[mi][ni], 0, 0, 0);
                acc[mi][ni] = __builtin_amdgcn_mfma_f32_16x16x32_bf16(al, bh[ni], acc[mi][ni], 0, 0, 0);
                acc[mi][ni] = __builtin_amdgcn_mfma_f32_16x16x32_bf16(ah, bl[ni], acc[mi][ni], 0, 0, 0);
            }
        }
        __syncthreads();
    }

    // ---- epilogue: D row=(l>>4)*4+r (t), col=l&15 (h); add bias ----
    const int tb = tch * 128;
    #pragma unroll
    for (int ni = 0; ni < 2; ++ni) {
        int col = n0 + w * 32 + ni * 16 + (l & 15);
        float bias = b_ih[col];
        #pragma unroll
        for (int mi = 0; mi < 8; ++mi)
            #pragma unroll
            for (int r = 0; r < 4; ++r) {
                int s = tb + mi * 16 + (l >> 4) * 4 + r;
                xw[((size_t)s * B_SZ + b) * H_DIM + col] = acc[mi][ni][r] + bias;
            }
    }
}

// =====================================================================
// Kernel 1b (fallback for small ws): VALU xw GEMM (proven rounds 2-8)
// =====================================================================
__global__ __launch_bounds__(256) void xw_gemm_kernel(
    const float* __restrict__ input, const float* __restrict__ W_ih,
    const float* __restrict__ b_ih, float* __restrict__ xw,
    int t0)
{
    __shared__ float Ash[32 * 68];
    __shared__ float Bsh[32 * 68];

    const int bm  = blockIdx.x >> 4;
    const int bn  = blockIdx.x & 15;
    const int tid = threadIdx.x;
    const int tx  = tid & 15;
    const int ty  = tid >> 4;

    const int t = t0 + bm;
    const float* Abase = input + (size_t)t * I_DIM;
    const float* Bbase = W_ih + (size_t)(bn * 64) * I_DIM;

    float acc[4][4] = {};

    for (int kt = 0; kt < I_DIM; kt += 32) {
        #pragma unroll
        for (int p = 0; p < 2; ++p) {
            int idx = tid + p * 256;
            int row = idx >> 3;
            int c4  = (idx & 7) << 2;
            float4 a = *(const float4*)(Abase + (size_t)row * (T_SEQ * I_DIM) + kt + c4);
            float4 b = *(const float4*)(Bbase + (size_t)row * I_DIM + kt + c4);
            Ash[(c4 + 0) * 68 + row] = a.x; Ash[(c4 + 1) * 68 + row] = a.y;
            Ash[(c4 + 2) * 68 + row] = a.z; Ash[(c4 + 3) * 68 + row] = a.w;
            Bsh[(c4 + 0) * 68 + row] = b.x; Bsh[(c4 + 1) * 68 + row] = b.y;
            Bsh[(c4 + 2) * 68 + row] = b.z; Bsh[(c4 + 3) * 68 + row] = b.w;
        }
        __syncthreads();
        #pragma unroll
        for (int k = 0; k < 32; ++k) {
            float4 a4 = *(const float4*)&Ash[k * 68 + ty * 4];
            float4 b4 = *(const float4*)&Bsh[k * 68 + tx * 4];
            float av[4] = {a4.x, a4.y, a4.z, a4.w};
            float bv[4] = {b4.x, b4.y, b4.z, b4.w};
            #pragma unroll
            for (int i = 0; i < 4; ++i)
                #pragma unroll
                for (int j = 0; j < 4; ++j)
                    acc[i][j] += av[i] * bv[j];
        }
        __syncthreads();
    }

    const int ncol = bn * 64 + tx * 4;
    float4 bias = *(const float4*)(b_ih + ncol);
    #pragma unroll
    for (int i = 0; i < 4; ++i) {
        int b = ty * 4 + i;
        float4 v;
        v.x = acc[i][0] + bias.x; v.y = acc[i][1] + bias.y;
        v.z = acc[i][2] + bias.z; v.w = acc[i][3] + bias.w;
        *(float4*)(xw + ((size_t)bm * B_SZ + b) * H_DIM + ncol) = v;
    }
}

// =====================================================================
// Kernel 2: persistent MFMA recurrence, TAG-IN-DATA + COMPACT SENTINEL.
//  R8 core, with Phase A replaced by a 1-cache-line sentinel poll:
//  producers, after __syncthreads() (all waves have ISSUED their h
//  stores), have tid0 store the monotonic value t+1 to sent[bg*32+js].
//  Consumers Phase-A-poll the 32 sentinel words (128 B) until all >= t.
//  The sentinel is a HINT only — Phase B's full tag-verified load still
//  gates consumption (catches sentinel-ahead-of-data skew, 0xAA poison,
//  and replay staleness). Deadlock-free by the R5 ring argument.
// =====================================================================
__global__ __launch_bounds__(256, 1) void elman_recur_kernel(
    const float* __restrict__ xw,            // [tc][64][1024]
    const unsigned short* __restrict__ Whi,  // [1024][1024] bf16 hi plane
    const unsigned short* __restrict__ Wlo,  // [1024][1024] bf16 lo plane
    unsigned int* __restrict__ hbuf,         // [RING][64][1024] tagged words
    unsigned int* __restrict__ sent,         // [8][32] monotonic sentinels
    float* __restrict__ out,                 // [64][512][1024]
    int t0, int tc)
{
    extern __shared__ __align__(16) short smem[];
    short* hA  = smem;                        // [8][HROW] bf16 (single plane)
    float* red = (float*)(smem + RED_OFF);    // [4][2][16][16]

    const int tid = threadIdx.x;
    const int bg  = blockIdx.x & 7;     // batch group
    const int js  = blockIdx.x >> 3;    // j slice
    const int w   = tid >> 6;           // wave id (K-split)
    const int l   = tid & 63;           // lane
    const int b   = tid & 7;            // epilogue: batch
    const int jl  = tid >> 3;           // epilogue: local j (0..31)
    const int jg  = js * 32 + jl;
    const int bgl = bg * 8 + b;

    // ---- one-time: W B-fragments into registers (k-contiguous, B^T layout) ----
    short8 Bhi[2][8], Blo[2][8];
    {
        const int n  = l & 15;
        const int kb = (l >> 4) * 8;
        #pragma unroll
        for (int t2 = 0; t2 < 2; ++t2) {
            const unsigned short* rhi = Whi + (size_t)(js * 32 + t2 * 16 + n) * H_DIM;
            const unsigned short* rlo = Wlo + (size_t)(js * 32 + t2 * 16 + n) * H_DIM;
            #pragma unroll
            for (int ks = 0; ks < 8; ++ks) {
                int k = w * 256 + ks * 32 + kb;
                Bhi[t2][ks] = *(const short8*)(rhi + k);
                Blo[t2][ks] = *(const short8*)(rlo + k);
            }
        }
    }

    for (int s = 0; s < tc; ++s) {
        const int t = t0 + s;

        // prefetch xw (independent of h) before any waiting
        float pre = xw[((size_t)s * B_SZ + bgl) * H_DIM + jg];

        if (t > 0) {
            const unsigned tagw = (unsigned)(t - 1);
            const unsigned long long* grp = (const unsigned long long*)
                (hbuf + (size_t)((t - 1) & (RING - 1)) * B_SZ * H_DIM
                      + (size_t)bg * 8 * H_DIM);

            // ---- Phase A: 1-line sentinel poll (hint; 128 B per iteration) ----
            {
                const unsigned want = (unsigned)t;   // producers at step t-1 wrote t
                const unsigned* sgrp = sent + bg * 32;
                for (;;) {
                    unsigned sv = __hip_atomic_load(sgrp + (tid & 31), __ATOMIC_RELAXED,
                                                    __HIP_MEMORY_SCOPE_AGENT);
                    if (__syncthreads_and(sv >= want)) break;
                }
            }

            // ---- Phase B: full load + tag verify (the correctness gate) ----
            unsigned long long v[16];
            for (;;) {
                #pragma unroll
                for (int p = 0; p < 16; ++p)
                    v[p] = __hip_atomic_load(grp + p * 256 + tid, __ATOMIC_RELAXED,
                                             __HIP_MEMORY_SCOPE_AGENT);
                int ok = 1;
                #pragma unroll
                for (int p = 0; p < 16; ++p) {
                    ok &= (((unsigned)(v[p] >> 16) & 0xffffu) == tagw);
                    ok &= ((unsigned)(v[p] >> 48) == tagw);
                }
                if (__syncthreads_and(ok)) break;
            }

            // ---- unpack payloads -> bf16 plane in LDS ----
            #pragma unroll
            for (int p = 0; p < 16; ++p) {
                int q   = p * 256 + tid;          // u64 pair index 0..4095
                int row = q >> 9;                 // 0..7
                int c   = (q & 511) * 2;          // 0..1022
                unsigned lo32 = (unsigned)v[p];
                unsigned hi32 = (unsigned)(v[p] >> 32);
                *(unsigned*)(hA + row * HROW + c) = (lo32 & 0xffffu) | (hi32 << 16);
            }
            __syncthreads();   // B1: staging done

            // ---- MFMA: this wave's K range, 2 N-tiles, 2 passes (Whi+Wlo) ----
            f32x4 acc0 = {0.f, 0.f, 0.f, 0.f};
            f32x4 acc1 = {0.f, 0.f, 0.f, 0.f};
            const short* aAb = hA + (l & 7) * HROW + w * 256 + ((l >> 4) * 8);
            #pragma unroll
            for (int ks = 0; ks < 8; ++ks) {
                short8 ah = *(const short8*)(aAb + ks * 32);
                acc0 = __builtin_amdgcn_mfma_f32_16x16x32_bf16(ah, Bhi[0][ks], acc0, 0, 0, 0);
                acc1 = __builtin_amdgcn_mfma_f32_16x16x32_bf16(ah, Bhi[1][ks], acc1, 0, 0, 0);
                acc0 = __builtin_amdgcn_mfma_f32_16x16x32_bf16(ah, Blo[0][ks], acc0, 0, 0, 0);
                acc1 = __builtin_amdgcn_mfma_f32_16x16x32_bf16(ah, Blo[1][ks], acc1, 0, 0, 0);
            }
            // partials -> LDS  (D layout: col = l&15, row = (l>>4)*4 + reg)
            *(f32x4*)&red[((w * 2 + 0) * 16 + (l & 15)) * 16 + (l >> 4) * 4] = acc0;
            *(f32x4*)&red[((w * 2 + 1) * 16 + (l & 15)) * 16 + (l >> 4) * 4] = acc1;
            __syncthreads();   // B2: partials visible (also fences hA reads)

            // reduce 4 wave-partials for this thread's (b, jl)
            const int tt = jl >> 4, c = jl & 15;
            #pragma unroll
            for (int w2 = 0; w2 < 4; ++w2)
                pre += red[((w2 * 2 + tt) * 16 + c) * 16 + b];
        }

        float hval = tanhf(pre);

        // publish tagged h_t (the store IS the completion signal)
        unsigned packed = ((unsigned)t << 16) | (unsigned)f2bf_rn(hval);
        __hip_atomic_store(hbuf + (size_t)(t & (RING - 1)) * B_SZ * H_DIM
                                + (size_t)bgl * H_DIM + jg,
                           packed, __ATOMIC_RELAXED, __HIP_MEMORY_SCOPE_AGENT);
        __builtin_nontemporal_store(hval, out + ((size_t)bgl * T_SEQ + t) * H_DIM + jg);

        // compact sentinel hint: all waves have ISSUED their stores -> tid0
        // publishes monotonic t+1 (no drain, no RMW; Phase B gates skew).
        __syncthreads();
        if (tid == 0)
            __hip_atomic_store(sent + bg * 32 + js, (unsigned)(t + 1),
                               __ATOMIC_RELAXED, __HIP_MEMORY_SCOPE_AGENT);
    }
}

// =====================================================================
extern "C" void kernel_launch(void* const* d_in, const int* in_sizes, int n_in,
                              void* d_out, int out_size, void* d_ws, size_t ws_size,
                              hipStream_t stream) {
    (void)in_sizes; (void)n_in; (void)out_size;
    const float* input = (const float*)d_in[0];   // [64,512,512]
    const float* W_ih  = (const float*)d_in[1];   // [1024,512]
    const float* b_ih  = (const float*)d_in[2];   // [1024]
    const float* W_hh  = (const float*)d_in[3];   // [1024,1024]
    float* out = (float*)d_out;

    char* ws = (char*)d_ws;
    // layout: hbuf ring 1M | sent 64K pad | Whh hi 2M | Whh lo 2M |
    //         Wih hi 1M | Wih lo 1M | xw ...
    unsigned int*   hbuf   = (unsigned int*)ws;
    unsigned int*   sent   = (unsigned int*)(ws + (1 << 20));
    unsigned short* Whh_hi = (unsigned short*)(ws + (1 << 20) + (64 << 10));
    unsigned short* Whh_lo = (unsigned short*)(ws + (3 << 20) + (64 << 10));
    unsigned short* Wih_hi = (unsigned short*)(ws + (5 << 20) + (64 << 10));
    unsigned short* Wih_lo = (unsigned short*)(ws + (6 << 20) + (64 << 10));
    const size_t    xw_off = (size_t)(7 << 20) + (64 << 10);
    float*          xwbuf  = (float*)(ws + xw_off);

    const size_t slice_bytes = (size_t)B_SZ * H_DIM * sizeof(float);  // 256 KB/t
    size_t avail = ws_size > xw_off ? ws_size - xw_off : 0;
    int Tc = (int)(avail / slice_bytes);
    if (Tc > T_SEQ) Tc = T_SEQ;
    bool mfma_xw = (Tc >= 128);
    if (mfma_xw) Tc &= ~127;          // multiple of 128 for the tiled GEMM
    if (Tc < 1)  Tc = 1;

    hipFuncSetAttribute((const void*)elman_recur_kernel,
                        hipFuncAttributeMaxDynamicSharedMemorySize,
                        RECUR_LDS_BYTES);

    // per-launch: reset sentinels (cheap; keeps the hint live across replays)
    hipMemsetAsync(sent, 0, 8 * 32 * sizeof(unsigned int), stream);

    // one-time splits (stream-ordered)
    wsplit_kernel<<<dim3(4096), dim3(256), 0, stream>>>(
        W_hh, Whh_hi, Whh_lo, H_DIM * H_DIM);
    wsplit_kernel<<<dim3(2048), dim3(256), 0, stream>>>(
        W_ih, Wih_hi, Wih_lo, H_DIM * I_DIM);

    for (int t0 = 0; t0 < T_SEQ; t0 += Tc) {
        int tc = (T_SEQ - t0 < Tc) ? (T_SEQ - t0) : Tc;

        if (mfma_xw && (tc % 128) == 0) {
            int ntch = tc / 128;
            xw_mfma_kernel<<<dim3(8 * 64 * ntch), dim3(256), 0, stream>>>(
                input, Wih_hi, Wih_lo, b_ih, xwbuf, t0, ntch);
        } else {
            xw_gemm_kernel<<<dim3((unsigned)tc * 16), dim3(256), 0, stream>>>(
                input, W_ih, b_ih, xwbuf, t0);
        }

        // plain launch (graph-capture-safe, proven): 148 KB LDS -> 1 block/CU,
        // grid 256 == CU count -> co-resident.
        elman_recur_kernel<<<dim3(256), dim3(256), RECUR_LDS_BYTES, stream>>>(
            xwbuf, Whh_hi, Whh_lo, hbuf, sent, out, t0, tc);
    }
}